// Round 1
// baseline (203.524 us; speedup 1.0000x reference)
//
#include <hip/hip_runtime.h>

#define U_   2048
#define T_   200
#define S_   10
#define K_   20
#define H_   16
#define DU_  32
#define DE_  32
#define DIN_ 264   // 32 + 11 + 220 + 1

// ---------------------------------------------------------------------------
// Kernel 1: pre[u,t,h] = b_rnn[h] + x[u,t,:] . Wx[:,h]
// x = [emb(32) | q(10)+zero | f(200)+zeros(20) | ctime]
// Thread-per-(u,t); Wx in LDS (uniform broadcast reads); float4 feature loads.
// ---------------------------------------------------------------------------
__global__ __launch_bounds__(256) void k_pre(
    const float* __restrict__ q, const float* __restrict__ f,
    const int* __restrict__ docid, const float* __restrict__ ct,
    const float* __restrict__ emb, const float* __restrict__ Wx,
    const float* __restrict__ brnn, float* __restrict__ pre)
{
    __shared__ float wx[DIN_ * H_];   // 16896 B
    __shared__ float bsh[H_];
    const int tid = threadIdx.x;
    for (int i = tid; i < DIN_ * H_; i += 256) wx[i] = Wx[i];
    if (tid < H_) bsh[tid] = brnn[tid];
    __syncthreads();

    const int idx = blockIdx.x * 256 + tid;      // 1600*256 == 409600 exact

    float acc[H_];
#pragma unroll
    for (int h = 0; h < H_; ++h) acc[h] = bsh[h];

    // ---- embedding part: Wx rows 0..31 ----
    const float4* e4 = (const float4*)(emb + (size_t)docid[idx] * DE_);
#pragma unroll
    for (int r = 0; r < DE_ / 4; ++r) {
        float4 v = e4[r];
        const float* w0 = &wx[(r * 4 + 0) * H_];
        const float* w1 = &wx[(r * 4 + 1) * H_];
        const float* w2 = &wx[(r * 4 + 2) * H_];
        const float* w3 = &wx[(r * 4 + 3) * H_];
#pragma unroll
        for (int h = 0; h < H_; ++h)
            acc[h] += v.x * w0[h] + v.y * w1[h] + v.z * w2[h] + v.w * w3[h];
    }

    // ---- quality part: Wx rows 32..41 (row 42 is the appended zero) ----
    const float2* q2 = (const float2*)(q + (size_t)idx * S_);   // 8B aligned (40B rows)
#pragma unroll
    for (int r = 0; r < S_ / 2; ++r) {
        float2 v = q2[r];
        const float* w0 = &wx[(DE_ + r * 2 + 0) * H_];
        const float* w1 = &wx[(DE_ + r * 2 + 1) * H_];
#pragma unroll
        for (int h = 0; h < H_; ++h)
            acc[h] += v.x * w0[h] + v.y * w1[h];
    }

    // ---- features part: Wx rows 43..242 (243..262 are the appended zero row) ----
    const float4* f4 = (const float4*)(f + (size_t)idx * (S_ * K_)); // 800B rows, 16B aligned
#pragma unroll 2
    for (int r = 0; r < (S_ * K_) / 4; ++r) {
        float4 v = f4[r];
        const int row = DE_ + S_ + 1 + r * 4;    // 43 + 4r
        const float* w0 = &wx[(row + 0) * H_];
        const float* w1 = &wx[(row + 1) * H_];
        const float* w2 = &wx[(row + 2) * H_];
        const float* w3 = &wx[(row + 3) * H_];
#pragma unroll
        for (int h = 0; h < H_; ++h)
            acc[h] += v.x * w0[h] + v.y * w1[h] + v.z * w2[h] + v.w * w3[h];
    }

    // ---- ctime: Wx row 263 ----
    {
        float c = ct[idx];
        const float* w = &wx[(DIN_ - 1) * H_];
#pragma unroll
        for (int h = 0; h < H_; ++h) acc[h] += c * w[h];
    }

    float4* o = (float4*)(pre + (size_t)idx * H_);
    o[0] = make_float4(acc[0], acc[1], acc[2], acc[3]);
    o[1] = make_float4(acc[4], acc[5], acc[6], acc[7]);
    o[2] = make_float4(acc[8], acc[9], acc[10], acc[11]);
    o[3] = make_float4(acc[12], acc[13], acc[14], acc[15]);
}

// ---------------------------------------------------------------------------
// Kernel 2: sequential RNN scan per user (16 lanes = 16 h-components),
// fused LeakyReLU + Dense(32).
// h@Wh via xor-butterfly: acc_l = sum_k shfl_xor(h,k)[=h[l^k]] * Wh[l^k][l]
// ---------------------------------------------------------------------------
__device__ __forceinline__ float tanh_fast(float x) {
    float e = __expf(2.f * x);          // v_exp_f32 based
    return 1.f - 2.f / (e + 1.f);       // exact limits at +/-inf
}

__global__ __launch_bounds__(64) void k_rnn(
    const float* __restrict__ pre, const int* __restrict__ docid,
    const float* __restrict__ Wh, const float* __restrict__ Wd,
    const float* __restrict__ bd, float* __restrict__ out)
{
    const int tid = threadIdx.x;
    const int l = tid & 15;
    const int u = (blockIdx.x * 64 + tid) >> 4;     // 512 blocks * 4 users

    const float* prow = pre + (size_t)u * T_ * H_;
    const int* drow = docid + (size_t)u * T_;

    float wh[16];
#pragma unroll
    for (int k = 0; k < 16; ++k) wh[k] = Wh[((l ^ k) << 4) | l];

    float h = 0.f;

    // 4-deep prefetch pipeline, static register indexing via unroll-by-4
    float pb0 = prow[0 * H_ + l], pb1 = prow[1 * H_ + l],
          pb2 = prow[2 * H_ + l], pb3 = prow[3 * H_ + l];
    int   m0 = drow[0], m1 = drow[1], m2 = drow[2], m3 = drow[3];

    for (int tb = 0; tb < T_; tb += 4) {
#pragma unroll
        for (int s = 0; s < 4; ++s) {
            float p; int m;
            if      (s == 0) { p = pb0; m = m0; }
            else if (s == 1) { p = pb1; m = m1; }
            else if (s == 2) { p = pb2; m = m2; }
            else             { p = pb3; m = m3; }

            int tn = tb + 4 + s; if (tn > T_ - 1) tn = T_ - 1;
            float pn = prow[tn * H_ + l];
            int   mn = drow[tn];
            if      (s == 0) { pb0 = pn; m0 = mn; }
            else if (s == 1) { pb1 = pn; m1 = mn; }
            else if (s == 2) { pb2 = pn; m2 = mn; }
            else             { pb3 = pn; m3 = mn; }

            float a0 = p, a1 = 0.f, a2 = 0.f, a3 = 0.f;
#pragma unroll
            for (int k = 0; k < 16; k += 4) {
                a0 += __shfl_xor(h, k + 0, 16) * wh[k + 0];
                a1 += __shfl_xor(h, k + 1, 16) * wh[k + 1];
                a2 += __shfl_xor(h, k + 2, 16) * wh[k + 2];
                a3 += __shfl_xor(h, k + 3, 16) * wh[k + 3];
            }
            float accv = (a0 + a1) + (a2 + a3);
            float th = tanh_fast(accv);
            h = (m != 0) ? th : h;      // mask_zero: keep previous h
        }
    }

    // LeakyReLU(0.3)
    float a = (h >= 0.f) ? h : 0.3f * h;

    // Dense: out[u][c] = bd[c] + sum_j a[j] * Wd[j][c]; lane l does c=l and c=l+16
    float wd0[16], wd1[16];
#pragma unroll
    for (int k = 0; k < 16; ++k) {
        int j = l ^ k;
        wd0[k] = Wd[j * DU_ + l];
        wd1[k] = Wd[j * DU_ + l + 16];
    }
    float o0 = bd[l], o1 = bd[l + 16];
#pragma unroll
    for (int k = 0; k < 16; ++k) {
        float av = __shfl_xor(a, k, 16);
        o0 += av * wd0[k];
        o1 += av * wd1[k];
    }
    out[(size_t)u * DU_ + l] = o0;
    out[(size_t)u * DU_ + l + 16] = o1;
}

// ---------------------------------------------------------------------------
extern "C" void kernel_launch(void* const* d_in, const int* in_sizes, int n_in,
                              void* d_out, int out_size, void* d_ws, size_t ws_size,
                              hipStream_t stream) {
    const float* q     = (const float*)d_in[0];  // [U,T,S]
    const float* f     = (const float*)d_in[1];  // [U,T,S,K]
    const int*   docid = (const int*)  d_in[2];  // [U,T]
    const float* ct    = (const float*)d_in[3];  // [U,T]
    const float* emb   = (const float*)d_in[4];  // [V+1,DE]
    const float* Wx    = (const float*)d_in[5];  // [DIN,H]
    const float* Wh    = (const float*)d_in[6];  // [H,H]
    const float* brnn  = (const float*)d_in[7];  // [H]
    const float* Wd    = (const float*)d_in[8];  // [H,DU]
    const float* bd    = (const float*)d_in[9];  // [DU]
    float* out = (float*)d_out;

    float* pre = (float*)d_ws;                   // U*T*H floats = 26.2 MB

    k_pre<<<(U_ * T_) / 256, 256, 0, stream>>>(q, f, docid, ct, emb, Wx, brnn, pre);
    k_rnn<<<(U_ * H_) / 64, 64, 0, stream>>>(pre, docid, Wh, Wd, bd, out);
}